// Round 7
// baseline (158.551 us; speedup 1.0000x reference)
//
#include <hip/hip_runtime.h>
#include <hip/hip_bf16.h>
#include <math.h>

// spatialAttention: B=512, P=128, D=64, domain 12x12, W [64,128], out [512,128,64] f32
#define NB 512
#define NP 128
#define ND 64
#define EPSF 1e-5f
// bf16-element row stride for MFMA-read LDS arrays: 136 elems = 272 B.
// 272 % 16 == 0 -> every short8 frag access is 16B-aligned; frag-read bank
// aliasing is 2-way (free per m136).
#define SW 136

typedef __attribute__((ext_vector_type(8))) short short8;   // 8 bf16 = 4 VGPRs
typedef __attribute__((ext_vector_type(4))) float f32x4;    // MFMA accumulator

__device__ __forceinline__ short f2bf(float x) {
    __hip_bfloat16 h = __float2bfloat16(x);
    return *reinterpret_cast<short*>(&h);
}

// bin = floor(x/30) clamped to [0,11]. f64 multiply by RN64(1/30) then RN to
// f32 agrees with numpy's RN32(x/30) except w.p. ~2^-29/elem. x >= 0 here.
__device__ __forceinline__ int bin30(float x) {
    float t = (float)((double)x * (1.0 / 30.0));
    int i = (int)t;
    return i < 0 ? 0 : (i > 11 ? 11 : i);
}

__device__ __forceinline__ float fast_tanh(float x) {
    float e = __expf(2.0f * x);                    // ~1 ulp native exp
    return 1.0f - 2.0f * __builtin_amdgcn_rcpf(e + 1.0f);
}

// W as bf16 [64][128], produced by prep kernel each launch (graph-safe).
__device__ __align__(16) short g_wbf[ND * 2 * ND];

__global__ __launch_bounds__(256) void prep_w(const float* __restrict__ W) {
    int idx = blockIdx.x * 256 + threadIdx.x;     // 2048 float4
    float4 v = ((const float4*)W)[idx];
    short4 s4;
    s4.x = f2bf(v.x); s4.y = f2bf(v.y); s4.z = f2bf(v.z); s4.w = f2bf(v.w);
    *(short4*)&g_wbf[idx * 4] = s4;
}

// 2 blocks per batch (rows [half*64, half*64+64)), 256 threads = 4 waves,
// wave owns 16 rows. LDS ~36 KB -> 4 blocks/CU, 16 waves/CU, one barrier.
//   phase 1: UNNORMALIZED E = exp(w)+eps (masked) -> bf16 LDS. 4-deep
//            software pipeline: groups 0-3 (12 float4, ~48 VGPRs) issued
//            BEFORE the staging barrier so their latency rides the drain;
//            group i+4 issues while group i computes (R6 post-mortem:
//            limiter = duty cycle of outstanding loads, not request size).
//   phase 2: E@h + ones-MFMA row sums (K=128); scale by 1/(s+eps) during the
//            C->A LDS round-trip; append h from s_hT columns (no global).
//   phase 3: out = fast_tanh(fused @ W^T + b), W-frags from g_wbf (L2-hot).
__global__ __launch_bounds__(256, 4) void spatial_attn_kernel(
    const float* __restrict__ hidden,   // [B,P,D]
    const float* __restrict__ dist,     // [B,P,P]
    const float* __restrict__ bear,     // [B,P,P]
    const float* __restrict__ head,     // [B,P,P]
    const float* __restrict__ smask,    // [B,P]
    const float* __restrict__ domain,   // [12,12]
    const float* __restrict__ bias,     // [D]
    float* __restrict__ out)            // [B,P,D]
{
    __shared__ __align__(16) short s_w[64 * SW];   // 17408 B: E, then [wh|h]
    __shared__ __align__(16) short s_hT[ND * SW];  // 17408 B: s_hT[d][q] = h[q][d]
    __shared__ float s_dom[144];
    __shared__ float s_mask[NP];

    const int blk  = blockIdx.x;
    const int b    = blk >> 1;
    const int half = blk & 1;
    const int tid  = threadIdx.x;
    const int lane = tid & 63;
    const int wave = tid >> 6;          // 0..3
    const int quad = lane >> 4;
    const int l16  = lane & 15;

    const int R0L = wave * 16;            // local row base (of 64)
    const int P0  = half * 64 + R0L;      // row base within batch (of 128)
    const size_t rowbase = (size_t)b * NP * NP;

    // Each lane owns 4 consecutive q of one of 2 rows per pipeline group.
    const int rsel = lane >> 5;           // 0 or 1: which of the 2 rows
    const int q0   = (lane & 31) * 4;     // column base within the row
    // group g covers rows P0 + 2g + rsel, g = 0..7
    const size_t ro0 = rowbase + (size_t)(P0 + rsel) * NP + q0;

    // ---- stage hidden^T as bf16 (swizzled: transpose writes 4-way) ----
    {
        const float4* hsrc = (const float4*)(hidden + (size_t)b * NP * ND);
        #pragma unroll
        for (int i = 0; i < 8; ++i) {
            int idx = i * 256 + ((tid & 15) * 16 + (tid >> 4));
            float4 v = hsrc[idx];
            int q = idx >> 4;
            int d = (idx & 15) * 4;
            s_hT[(d + 0) * SW + q] = f2bf(v.x);
            s_hT[(d + 1) * SW + q] = f2bf(v.y);
            s_hT[(d + 2) * SW + q] = f2bf(v.z);
            s_hT[(d + 3) * SW + q] = f2bf(v.w);
        }
    }
    // ---- phase-1 pipeline prologue: groups 0..3 in flight across barrier ----
    float4 dqr[4], bqr[4], hqr[4];
    #pragma unroll
    for (int g = 0; g < 4; ++g) {
        const size_t ro = ro0 + (size_t)g * (2 * NP);
        dqr[g] = *(const float4*)&dist[ro];
        bqr[g] = *(const float4*)&bear[ro];
        hqr[g] = *(const float4*)&head[ro];
    }
    if (tid < 144) s_dom[tid] = domain[tid];
    if (tid < NP)  s_mask[tid] = smask[b * NP + tid];
    __syncthreads();   // the only block-wide barrier

    const float4 mqv = *(const float4*)&s_mask[q0];   // masks for q0..q0+3

    // ---- phase 1: 4-deep pipelined masked-exp; group i+4 issues under i ----
    #pragma unroll
    for (int i = 0; i < 8; ++i) {
        float4 dq = dqr[i & 3], bq = bqr[i & 3], hq = hqr[i & 3];
        if (i < 4) {
            const size_t ro = ro0 + (size_t)(i + 4) * (2 * NP);
            dqr[i & 3] = *(const float4*)&dist[ro];
            bqr[i & 3] = *(const float4*)&bear[ro];
            hqr[i & 3] = *(const float4*)&head[ro];
        }
        const int p  = P0 + 2 * i + rsel;             // row within batch
        const int rl = R0L + 2 * i + rsel;            // local row in s_w
        const float mp = s_mask[p];

        float hv[4] = {hq.x, hq.y, hq.z, hq.w};
        float bv[4] = {bq.x, bq.y, bq.z, bq.w};
        float dv[4] = {dq.x, dq.y, dq.z, dq.w};
        float mv[4] = {mqv.x, mqv.y, mqv.z, mqv.w};
        short ex[4];
        #pragma unroll
        for (int c = 0; c < 4; ++c) {
            int i1 = bin30(hv[c]), i2 = bin30(bv[c]);
            float wv = s_dom[i1 * 12 + i2] - dv[c];
            bool on = (wv > 0.0f) && (mp != 0.0f) && (mv[c] != 0.0f) && (q0 + c != p);
            ex[c] = f2bf(on ? (__expf(wv) + EPSF) : EPSF);
        }
        short4 res; res.x = ex[0]; res.y = ex[1]; res.z = ex[2]; res.w = ex[3];
        *(short4*)&s_w[rl * SW + q0] = res;           // 8B-aligned ds_write_b64
    }

    // ---- phase 2: wh_unnorm = E @ h + ones-MFMA row sums (K=128) ----
    f32x4 acc[4], accs;
    #pragma unroll
    for (int tj = 0; tj < 4; ++tj) acc[tj] = (f32x4){0.f, 0.f, 0.f, 0.f};
    accs = (f32x4){0.f, 0.f, 0.f, 0.f};

    short8 ones;
    #pragma unroll
    for (int i = 0; i < 8; ++i) ones[i] = (short)0x3F80;  // bf16 1.0

    #pragma unroll
    for (int kb = 0; kb < 4; ++kb) {
        const int ko = kb * 32 + quad * 8;
        short8 a = *(const short8*)&s_w[(R0L + l16) * SW + ko];
        accs = __builtin_amdgcn_mfma_f32_16x16x32_bf16(a, ones, accs, 0, 0, 0);
        #pragma unroll
        for (int tj = 0; tj < 4; ++tj) {
            short8 bf = *(const short8*)&s_hT[(tj * 16 + l16) * SW + ko];
            acc[tj] = __builtin_amdgcn_mfma_f32_16x16x32_bf16(a, bf, acc[tj], 0, 0, 0);
        }
    }

    // C/D row = quad*4 + r; accs rows match lane-for-lane.
    float inv[4];
    #pragma unroll
    for (int r = 0; r < 4; ++r) inv[r] = 1.0f / (accs[r] + EPSF);

    // ---- build fused rows [wh | h] in s_w (wave-local; DS is in-order) ----
    #pragma unroll
    for (int tj = 0; tj < 4; ++tj)
        #pragma unroll
        for (int r = 0; r < 4; ++r) {
            int row = R0L + quad * 4 + r;
            s_w[row * SW + tj * 16 + l16] = f2bf(acc[tj][r] * inv[r]);
        }
    // h columns straight from s_hT (bf16 passthrough; no global traffic).
    #pragma unroll 4
    for (int i = 0; i < 16; ++i)
        s_w[(R0L + i) * SW + 64 + lane] = s_hT[lane * SW + (P0 + i)];

    // ---- phase 3: out = tanh(fused @ W^T + b), B-frags from g_wbf (L2) ----
    f32x4 acc2[4];
    #pragma unroll
    for (int tj = 0; tj < 4; ++tj) acc2[tj] = (f32x4){0.f, 0.f, 0.f, 0.f};

    #pragma unroll
    for (int kb = 0; kb < 4; ++kb) {
        const int ko = kb * 32 + quad * 8;
        short8 a = *(const short8*)&s_w[(R0L + l16) * SW + ko];
        #pragma unroll
        for (int tj = 0; tj < 4; ++tj) {
            short8 bf = *(const short8*)&g_wbf[(tj * 16 + l16) * (2 * ND) + ko];
            acc2[tj] = __builtin_amdgcn_mfma_f32_16x16x32_bf16(a, bf, acc2[tj], 0, 0, 0);
        }
    }

    float bvals[4];
    #pragma unroll
    for (int tj = 0; tj < 4; ++tj) bvals[tj] = bias[tj * 16 + l16];

    float* ob = out + ((size_t)b * NP + half * 64) * ND;
    #pragma unroll
    for (int tj = 0; tj < 4; ++tj)
        #pragma unroll
        for (int r = 0; r < 4; ++r) {
            int row = R0L + quad * 4 + r;
            ob[(size_t)row * ND + tj * 16 + l16] = fast_tanh(acc2[tj][r] + bvals[tj]);
        }
}

extern "C" void kernel_launch(void* const* d_in, const int* in_sizes, int n_in,
                              void* d_out, int out_size, void* d_ws, size_t ws_size,
                              hipStream_t stream) {
    const float* hidden = (const float*)d_in[0];
    const float* dist   = (const float*)d_in[1];
    const float* bear   = (const float*)d_in[2];
    const float* head   = (const float*)d_in[3];
    const float* smask  = (const float*)d_in[4];
    const float* domain = (const float*)d_in[5];
    const float* W      = (const float*)d_in[6];
    const float* bias   = (const float*)d_in[7];
    float* out = (float*)d_out;

    prep_w<<<dim3(8), dim3(256), 0, stream>>>(W);
    spatial_attn_kernel<<<dim3(NB * 2), dim3(256), 0, stream>>>(
        hidden, dist, bear, head, smask, domain, bias, out);
}